// Round 7
// baseline (321.114 us; speedup 1.0000x reference)
//
#include <hip/hip_runtime.h>
#include <stdint.h>

// Causal SDPA B=4,H=16,S=2048,D=64 fp32. Flash-MFMA bf16, round 7.
// convert_prep: UNCHANGED (control; part of the fixed ~112us floor).
// sdpa_mfma v7: register-resident P. S^T = K*Q^T via 16x16x32 gives C-layout
//   (query=lane&15, key=quad*4+reg) == A-layout of mfma_f32_16x16x16_bf16.
//   => PV uses 16x16x16 MFMA with P packed in-register from the exp'd QK
//   output: NO LDS round-trip, NO bpermute, NO bank conflicts.
//   V B-frags (keys quad*4+{0..3} at fixed d) are contiguous 8B in V^T [d][key].
// Chain structure (r6): pair-chain (c, 63-c) = 33 steps, split 17/16 across
//   2 waves; block = chains {2cp, 2cp+1} so paired waves walk IDENTICAL key
//   sequences (L1 sharing). 1024 blocks x 256 thr = 16 waves/CU. One barrier.

#define SLEN 2048
#define DHEAD 64
#define NHEADS 64
#define NELEM (SLEN * DHEAD * NHEADS)   // 8388608 per tensor

typedef short bf16x8 __attribute__((ext_vector_type(8)));
typedef short bf16x4 __attribute__((ext_vector_type(4)));
typedef float f32x4 __attribute__((ext_vector_type(4)));

__device__ __forceinline__ uint32_t pkbf(float hi, float lo) {
    uint32_t a = __builtin_bit_cast(uint32_t, lo) + 0x8000u;
    uint32_t b = __builtin_bit_cast(uint32_t, hi) + 0x8000u;
    return __builtin_amdgcn_perm(b, a, 0x07060302u);
}
__device__ __forceinline__ unsigned short f2bf(float f) {
    return (unsigned short)((__builtin_bit_cast(uint32_t, f) + 0x8000u) >> 16);
}

__device__ __forceinline__ f32x4 mfma16(bf16x4 a, bf16x4 b, f32x4 c) {
#if __has_builtin(__builtin_amdgcn_mfma_f32_16x16x16bf16_1k)
    return __builtin_amdgcn_mfma_f32_16x16x16bf16_1k(a, b, c, 0, 0, 0);
#else
    asm volatile("v_mfma_f32_16x16x16_bf16 %0, %1, %2, %0" : "+v"(c) : "v"(a), "v"(b));
    return c;
#endif
}

// ---------------- pass 1: K straight, V transposed (identical to rounds 3-6) ----------------
__global__ __launch_bounds__(256)
void convert_prep(const float* __restrict__ K, const float* __restrict__ V,
                  unsigned short* __restrict__ Kb, unsigned short* __restrict__ Vtb) {
    __shared__ unsigned short Lt[64 * 264];
    const int b = blockIdx.x, t = threadIdx.x;
    if (b < 4096) {
        const int off = (b * 256 + t) * 8;
        float4 a = *(const float4*)(K + off);
        float4 c = *(const float4*)(K + off + 4);
        uint4 o;
        o.x = pkbf(a.y, a.x); o.y = pkbf(a.w, a.z);
        o.z = pkbf(c.y, c.x); o.w = pkbf(c.w, c.z);
        *(uint4*)(Kb + off) = o;
    } else {
        const int vb2 = b - 4096;
        const int head = vb2 >> 3, kblk = vb2 & 7;
        const float* Vh = V + (size_t)head * (SLEN * DHEAD) + kblk * 256 * DHEAD;
        unsigned short* Vo = Vtb + (size_t)head * (SLEN * DHEAD) + kblk * 256;
#pragma unroll
        for (int i = 0; i < 16; ++i) {
            int idx = t + 256 * i;
            int key = idx >> 4, d4 = idx & 15;
            float4 v = *(const float4*)(Vh + key * DHEAD + d4 * 4);
            Lt[(d4 * 4 + 0) * 264 + key] = f2bf(v.x);
            Lt[(d4 * 4 + 1) * 264 + key] = f2bf(v.y);
            Lt[(d4 * 4 + 2) * 264 + key] = f2bf(v.z);
            Lt[(d4 * 4 + 3) * 264 + key] = f2bf(v.w);
        }
        __syncthreads();
#pragma unroll
        for (int jj = 0; jj < 8; ++jj) {
            int idx = t + 256 * jj;
            int d = idx >> 5, k8 = idx & 31;
            *(uint4*)(Vo + (size_t)d * SLEN + k8 * 8) = *(const uint4*)(Lt + d * 264 + k8 * 8);
        }
    }
}

// ---------------- pass 2: flash attention, register-resident P ----------------
__global__ __launch_bounds__(256, 4)
void sdpa_mfma(const float* __restrict__ Qf, const unsigned short* __restrict__ Kb,
               const unsigned short* __restrict__ Vtb, float* __restrict__ Og) {
    const int n = blockIdx.x;
    const int head = n & 63;
    const int cp = n >> 6;                 // 0..15
    const int tid = threadIdx.x;
    const int w = tid >> 6, lane = tid & 63;
    const int cl = lane & 15, quad = lane >> 4;
    const int ch = w >> 1, role = w & 1;
    const int c = 2 * cp + ch;             // chains paired (2cp, 2cp+1): identical key walks
    const int subA = c, subB = 63 - c;     // 32q subtile indices
    const int Sa = (c >> 1) + 1;           // key-blocks for subA
    const int Sb = ((63 - c) >> 1) + 1;    // key-blocks for subB; Sa+Sb == 33

    const size_t hb = (size_t)head * SLEN * DHEAD;
    const float* Qh = Qf + hb;
    const unsigned short* Kh = Kb + hb;    // [key][d]
    const unsigned short* Vth = Vtb + hb;  // [d][key]
    float* Oh = Og + hb;

    __shared__ float Om[2][64 * 36];       // merge buffer [chain][col d][row q]
    __shared__ float Lsm[2][32];

    const float SCL = 0.18033688f;         // (1/sqrt(64)) * log2(e), folded into Q

    bf16x8 qf[2][2];
    f32x4 o[2][4];
    float ls[2];

    auto load_qf = [&](int i) {
#pragma unroll
        for (int m = 0; m < 2; ++m)
#pragma unroll
            for (int h = 0; h < 2; ++h) {
                const float* src = Qh + (size_t)(i * 32 + m * 16 + cl) * DHEAD + h * 32 + quad * 8;
                float4 a = *(const float4*)src;
                float4 b = *(const float4*)(src + 4);
                uint4 u;
                u.x = pkbf(a.y * SCL, a.x * SCL); u.y = pkbf(a.w * SCL, a.z * SCL);
                u.z = pkbf(b.y * SCL, b.x * SCL); u.w = pkbf(b.w * SCL, b.z * SCL);
                qf[m][h] = __builtin_bit_cast(bf16x8, u);
            }
    };
    auto zero_acc = [&]() {
#pragma unroll
        for (int m = 0; m < 2; ++m) {
            ls[m] = 0.f;
#pragma unroll
            for (int d = 0; d < 4; ++d) o[m][d] = (f32x4){0.f, 0.f, 0.f, 0.f};
        }
    };

    // key-blocks [js,je) of 32q-subtile i (queries [32i,32i+32))
    auto do_steps = [&](int i, int js, int je) {
        const int jd = i >> 1;             // diagonal key-block
        const int qrb = 32 * (i & 1);
        for (int j = js; j < je; ++j) {
            const unsigned short* kjb = Kh + (size_t)j * 64 * DHEAD;   // uniform
            const unsigned short* vjb = Vth + (size_t)j * 64;          // uniform
            // K A-frags (16x16x32): key=16kk+cl, d=32h+quad*8
            bf16x8 kb[4][2];
#pragma unroll
            for (int kk = 0; kk < 4; ++kk)
#pragma unroll
                for (int h = 0; h < 2; ++h)
                    kb[kk][h] = __builtin_bit_cast(bf16x8,
                        *(const uint4*)(kjb + (kk * 16 + cl) * DHEAD + h * 32 + quad * 8));
            // V B-frags (16x16x16): d=dd*16+cl, keys=16kk+quad*4+{0..3} (8B contiguous)
            uint2 vb[4][4];
#pragma unroll
            for (int dd = 0; dd < 4; ++dd)
#pragma unroll
                for (int kk = 0; kk < 4; ++kk)
                    vb[dd][kk] = *(const uint2*)(vjb + (size_t)(dd * 16 + cl) * SLEN + kk * 16 + quad * 4);

            // S^T = K Q^T ; exp2 (Q pre-scaled) ; pack P in-register (A-layout!)
            bf16x4 pa[2][4];
            const bool partial = (j == jd);
#pragma unroll
            for (int kk = 0; kk < 4; ++kk) {
                const int krel = kk * 16 + quad * 4;
#pragma unroll
                for (int qq = 0; qq < 2; ++qq) {
                    f32x4 s = (f32x4){0.f, 0.f, 0.f, 0.f};
                    s = __builtin_amdgcn_mfma_f32_16x16x32_bf16(kb[kk][0], qf[qq][0], s, 0, 0, 0);
                    s = __builtin_amdgcn_mfma_f32_16x16x32_bf16(kb[kk][1], qf[qq][1], s, 0, 0, 0);
                    float p0, p1, p2, p3;
                    if (partial) {
                        const int qrel = qrb + qq * 16 + cl;
                        p0 = (krel + 0 <= qrel) ? __builtin_amdgcn_exp2f(s[0]) : 0.f;
                        p1 = (krel + 1 <= qrel) ? __builtin_amdgcn_exp2f(s[1]) : 0.f;
                        p2 = (krel + 2 <= qrel) ? __builtin_amdgcn_exp2f(s[2]) : 0.f;
                        p3 = (krel + 3 <= qrel) ? __builtin_amdgcn_exp2f(s[3]) : 0.f;
                    } else {
                        p0 = __builtin_amdgcn_exp2f(s[0]);
                        p1 = __builtin_amdgcn_exp2f(s[1]);
                        p2 = __builtin_amdgcn_exp2f(s[2]);
                        p3 = __builtin_amdgcn_exp2f(s[3]);
                    }
                    ls[qq] += (p0 + p1) + (p2 + p3);
                    uint2 pw;
                    pw.x = pkbf(p1, p0);
                    pw.y = pkbf(p3, p2);
                    pa[qq][kk] = __builtin_bit_cast(bf16x4, pw);
                }
            }
            // O += P V via 16x16x16 (P already in A-layout, V^T frags in B-layout)
#pragma unroll
            for (int kk = 0; kk < 4; ++kk)
#pragma unroll
                for (int dd = 0; dd < 4; ++dd) {
                    const bf16x4 vbf = __builtin_bit_cast(bf16x4, vb[dd][kk]);
#pragma unroll
                    for (int qq = 0; qq < 2; ++qq)
                        o[qq][dd] = mfma16(pa[qq][kk], vbf, o[qq][dd]);
                }
        }
    };
    auto reduce_ls = [&]() {
#pragma unroll
        for (int qq = 0; qq < 2; ++qq) {
            float v = ls[qq];
            v += __shfl_xor(v, 16);
            v += __shfl_xor(v, 32);
            ls[qq] = v;
        }
    };
    auto store_tile = [&](int i, const float* lsr) {
#pragma unroll
        for (int m = 0; m < 2; ++m)
#pragma unroll
            for (int r = 0; r < 4; ++r) {
                const float inv = 1.0f / __shfl(lsr[m], quad * 4 + r);
#pragma unroll
                for (int dd = 0; dd < 4; ++dd)
                    Oh[(size_t)(i * 32 + m * 16 + quad * 4 + r) * DHEAD + dd * 16 + cl] = o[m][dd][r] * inv;
            }
    };

    if (role == 0) {
        load_qf(subA); zero_acc();
        do_steps(subA, 0, Sa);             // subtile A complete (diag last)
        reduce_ls();
        store_tile(subA, ls);
        load_qf(subB); zero_acc();
        do_steps(subB, 0, Sb - 16);        // subtile B head (all full blocks)
        reduce_ls();
    } else {
        load_qf(subB); zero_acc();
        do_steps(subB, Sb - 16, Sb);       // subtile B tail (diag last)
        reduce_ls();
#pragma unroll
        for (int m = 0; m < 2; ++m)
#pragma unroll
            for (int dd = 0; dd < 4; ++dd)
                *(f32x4*)&Om[ch][(dd * 16 + cl) * 36 + m * 16 + quad * 4] = o[m][dd];
        if (quad == 0) {
#pragma unroll
            for (int qq = 0; qq < 2; ++qq) Lsm[ch][qq * 16 + cl] = ls[qq];
        }
    }
    __syncthreads();
    if (role == 0) {
#pragma unroll
        for (int m = 0; m < 2; ++m)
#pragma unroll
            for (int dd = 0; dd < 4; ++dd)
                o[m][dd] += *(const f32x4*)&Om[ch][(dd * 16 + cl) * 36 + m * 16 + quad * 4];
        float lc[2];
#pragma unroll
        for (int qq = 0; qq < 2; ++qq) lc[qq] = ls[qq] + Lsm[ch][qq * 16 + cl];
        store_tile(subB, lc);
    }
}

extern "C" void kernel_launch(void* const* d_in, const int* in_sizes, int n_in,
                              void* d_out, int out_size, void* d_ws, size_t ws_size,
                              hipStream_t stream) {
    const float* Q = (const float*)d_in[0];
    const float* K = (const float*)d_in[1];
    const float* V = (const float*)d_in[2];
    float*       O = (float*)d_out;

    unsigned short* Kbf  = (unsigned short*)d_ws;
    unsigned short* Vtbf = Kbf + NELEM;

    convert_prep<<<dim3(4096 + 512), dim3(256), 0, stream>>>(K, V, Kbf, Vtbf);
    sdpa_mfma<<<dim3(1024), dim3(256), 0, stream>>>(Q, Kbf, Vtbf, O);
}

// Round 8
// 220.659 us; speedup vs baseline: 1.4552x; 1.4552x over previous
//
#include <hip/hip_runtime.h>
#include <stdint.h>

// Causal SDPA B=4,H=16,S=2048,D=64 fp32. Flash-MFMA bf16, round 8.
// convert_prep: UNCHANGED (control; part of the fixed ~112us floor).
// sdpa_mfma v8 = r4 memory structure + r7 compute core:
//   - K & V^T tiles staged to XOR-swizzled LDS (coalesced global reads),
//     double-buffered -> ONE barrier per key-block step.
//   - S^T = K*Q^T (16x16x32); exp'd P stays IN REGISTERS (C-layout == A-layout
//     of 16x16x16) -> PV via mfma_f32_16x16x16_bf16. No P LDS, no bpermute.
//     (correctness of this path verified in round 7)
//   - V^T B-frags (keys kk*16+quad*4+{0..3} at d=dd*16+cl) = ds_read_b64 from
//     swizzled V^T tile; 2-way bank alias only (free per m136).
//   Block = (head, A): 4 waves x 32q; waves 0,1 -> tile A, waves 2,3 -> tile
//   B=31-A; shared staging stream, ntiles = 32-A. 1024 blocks x 256 thr.

#define SLEN 2048
#define DHEAD 64
#define NHEADS 64
#define NELEM (SLEN * DHEAD * NHEADS)   // 8388608 per tensor

typedef short bf16x8 __attribute__((ext_vector_type(8)));
typedef short bf16x4 __attribute__((ext_vector_type(4)));
typedef float f32x4 __attribute__((ext_vector_type(4)));

__device__ __forceinline__ uint32_t pkbf(float hi, float lo) {
    uint32_t a = __builtin_bit_cast(uint32_t, lo) + 0x8000u;
    uint32_t b = __builtin_bit_cast(uint32_t, hi) + 0x8000u;
    return __builtin_amdgcn_perm(b, a, 0x07060302u);
}
__device__ __forceinline__ unsigned short f2bf(float f) {
    return (unsigned short)((__builtin_bit_cast(uint32_t, f) + 0x8000u) >> 16);
}
__device__ __forceinline__ int swz(int row, int g) {  // offset in shorts, 64x64 tile
    return row * 64 + ((g ^ (row & 7)) << 3);
}
__device__ __forceinline__ f32x4 mfma16(bf16x4 a, bf16x4 b, f32x4 c) {
#if __has_builtin(__builtin_amdgcn_mfma_f32_16x16x16bf16_1k)
    return __builtin_amdgcn_mfma_f32_16x16x16bf16_1k(a, b, c, 0, 0, 0);
#else
    asm volatile("v_mfma_f32_16x16x16_bf16 %0, %1, %2, %0" : "+v"(c) : "v"(a), "v"(b));
    return c;
#endif
}

// ---------------- pass 1: K straight, V transposed (identical to rounds 3-7) ----------------
__global__ __launch_bounds__(256)
void convert_prep(const float* __restrict__ K, const float* __restrict__ V,
                  unsigned short* __restrict__ Kb, unsigned short* __restrict__ Vtb) {
    __shared__ unsigned short Lt[64 * 264];
    const int b = blockIdx.x, t = threadIdx.x;
    if (b < 4096) {
        const int off = (b * 256 + t) * 8;
        float4 a = *(const float4*)(K + off);
        float4 c = *(const float4*)(K + off + 4);
        uint4 o;
        o.x = pkbf(a.y, a.x); o.y = pkbf(a.w, a.z);
        o.z = pkbf(c.y, c.x); o.w = pkbf(c.w, c.z);
        *(uint4*)(Kb + off) = o;
    } else {
        const int vb2 = b - 4096;
        const int head = vb2 >> 3, kblk = vb2 & 7;
        const float* Vh = V + (size_t)head * (SLEN * DHEAD) + kblk * 256 * DHEAD;
        unsigned short* Vo = Vtb + (size_t)head * (SLEN * DHEAD) + kblk * 256;
#pragma unroll
        for (int i = 0; i < 16; ++i) {
            int idx = t + 256 * i;
            int key = idx >> 4, d4 = idx & 15;
            float4 v = *(const float4*)(Vh + key * DHEAD + d4 * 4);
            Lt[(d4 * 4 + 0) * 264 + key] = f2bf(v.x);
            Lt[(d4 * 4 + 1) * 264 + key] = f2bf(v.y);
            Lt[(d4 * 4 + 2) * 264 + key] = f2bf(v.z);
            Lt[(d4 * 4 + 3) * 264 + key] = f2bf(v.w);
        }
        __syncthreads();
#pragma unroll
        for (int jj = 0; jj < 8; ++jj) {
            int idx = t + 256 * jj;
            int d = idx >> 5, k8 = idx & 31;
            *(uint4*)(Vo + (size_t)d * SLEN + k8 * 8) = *(const uint4*)(Lt + d * 264 + k8 * 8);
        }
    }
}

// ---------------- pass 2: flash attention, staged LDS + register P ----------------
__global__ __launch_bounds__(256, 4)
void sdpa_mfma(const float* __restrict__ Qf, const unsigned short* __restrict__ Kb,
               const unsigned short* __restrict__ Vtb, float* __restrict__ Og) {
    const int n = blockIdx.x;
    const int head = n >> 4;               // 16 consecutive blocks share a head (L2)
    const int A = n & 15;                  // light tile 0..15
    const int Bt = 31 - A;                 // heavy tile 16..31

    const size_t hb = (size_t)head * SLEN * DHEAD;
    const float* Qh = Qf + hb;
    const unsigned short* Kh = Kb + hb;    // [key][d]
    const unsigned short* Vth = Vtb + hb;  // [d][2048]
    float* Oh = Og + hb;

    const int tid = threadIdx.x;
    const int w = tid >> 6, lane = tid & 63;
    const int cl = lane & 15, quad = lane >> 4;

    __shared__ unsigned short Kl[2][64 * 64];   // 16384 B, swizzled [key][d]
    __shared__ unsigned short Vl[2][64 * 64];   // 16384 B, swizzled [d][key]

    // waves 0,1 -> tile A halves; waves 2,3 -> tile B halves
    const int mytile = (w < 2) ? A : Bt;
    const int qw = mytile * 64 + (w & 1) * 32;
    const int qrb = (w & 1) * 32;

    // Q fragments (A-layout for QK's B-operand role): pre-scaled
    const float SCL = 0.18033688f;   // (1/sqrt(64)) * log2(e)
    bf16x8 qf[2][2];
#pragma unroll
    for (int m = 0; m < 2; ++m)
#pragma unroll
        for (int h = 0; h < 2; ++h) {
            const float* src = Qh + (size_t)(qw + m * 16 + cl) * DHEAD + h * 32 + quad * 8;
            float4 a = *(const float4*)src;
            float4 b = *(const float4*)(src + 4);
            uint4 u;
            u.x = pkbf(a.y * SCL, a.x * SCL); u.y = pkbf(a.w * SCL, a.z * SCL);
            u.z = pkbf(b.y * SCL, b.x * SCL); u.w = pkbf(b.w * SCL, b.z * SCL);
            qf[m][h] = __builtin_bit_cast(bf16x8, u);
        }

    f32x4 o[2][4];
#pragma unroll
    for (int m = 0; m < 2; ++m)
#pragma unroll
        for (int d = 0; d < 4; ++d) o[m][d] = (f32x4){0.f, 0.f, 0.f, 0.f};
    float ls[2] = {0.f, 0.f};

    // staging: 256 threads x 2 uint4 per tensor (tile = 512 uint4); LDS swizzled
    const int s1 = tid + 256;
    const int srow0 = tid >> 3, sg0 = tid & 7;
    const int srow1 = s1 >> 3,  sg1 = s1 & 7;
    const int lo0 = swz(srow0, sg0), lo1 = swz(srow1, sg1);
    const size_t kS0 = (size_t)srow0 * DHEAD + sg0 * 8, kS1 = (size_t)srow1 * DHEAD + sg1 * 8;
    const size_t vS0 = (size_t)srow0 * SLEN + sg0 * 8,  vS1 = (size_t)srow1 * SLEN + sg1 * 8;

    const int ntiles = Bt + 1;    // 17..32

    auto load_regs = [&](int t, uint4& k0r, uint4& k1r, uint4& v0r, uint4& v1r) {
        const int j = (t < ntiles) ? t : ntiles - 1;
        const size_t ko = (size_t)j * 64 * DHEAD;
        k0r = *(const uint4*)(Kh + kS0 + ko);
        k1r = *(const uint4*)(Kh + kS1 + ko);
        v0r = *(const uint4*)(Vth + vS0 + j * 64);
        v1r = *(const uint4*)(Vth + vS1 + j * 64);
    };

    uint4 kr0, kr1, vr0, vr1;
    // prologue: tile 0 -> buf0 ; tile 1 -> regs
    load_regs(0, kr0, kr1, vr0, vr1);
    *(uint4*)(Kl[0] + lo0) = kr0; *(uint4*)(Kl[0] + lo1) = kr1;
    *(uint4*)(Vl[0] + lo0) = vr0; *(uint4*)(Vl[0] + lo1) = vr1;
    load_regs(1, kr0, kr1, vr0, vr1);

    for (int t = 0; t < ntiles; ++t) {
        __syncthreads();   // separates: stage-writes(t) vs reads(t); reads(t-1) vs stage-writes(t+1)
        const int bw = (t + 1) & 1;
        if (t + 1 < ntiles) {
            *(uint4*)(Kl[bw] + lo0) = kr0; *(uint4*)(Kl[bw] + lo1) = kr1;
            *(uint4*)(Vl[bw] + lo0) = vr0; *(uint4*)(Vl[bw] + lo1) = vr1;
        }
        if (t + 2 < ntiles) load_regs(t + 2, kr0, kr1, vr0, vr1);

        if (t * 64 > qw + 31) continue;   // wave-uniform: tile above diagonal
        const bool partial = (t == mytile);   // 32q halves: diag block == mytile
        const unsigned short* Kt = Kl[t & 1];
        const unsigned short* Vt = Vl[t & 1];

#pragma unroll
        for (int kk = 0; kk < 4; ++kk) {
            // K A-frags: key=kk*16+cl, d=h*32+quad*8
            bf16x8 kb0 = __builtin_bit_cast(bf16x8, *(const uint4*)(Kt + swz(kk * 16 + cl, quad)));
            bf16x8 kb1 = __builtin_bit_cast(bf16x8, *(const uint4*)(Kt + swz(kk * 16 + cl, 4 + quad)));
            // V^T B-frags (16x16x16): d=dd*16+cl, keys=kk*16+quad*4+{0..3} -> b64
            uint2 vbr[4];
#pragma unroll
            for (int dd = 0; dd < 4; ++dd) {
                const int row = dd * 16 + cl;
                const int g = kk * 2 + (quad >> 1);
                vbr[dd] = *(const uint2*)(Vt + row * 64 + ((g ^ (row & 7)) << 3) + (quad & 1) * 4);
            }
            const int krel = kk * 16 + quad * 4;
            bf16x4 pa[2];
#pragma unroll
            for (int qq = 0; qq < 2; ++qq) {
                f32x4 s = (f32x4){0.f, 0.f, 0.f, 0.f};
                s = __builtin_amdgcn_mfma_f32_16x16x32_bf16(kb0, qf[qq][0], s, 0, 0, 0);
                s = __builtin_amdgcn_mfma_f32_16x16x32_bf16(kb1, qf[qq][1], s, 0, 0, 0);
                float p0, p1, p2, p3;
                if (partial) {
                    const int qrel = qrb + qq * 16 + cl;
                    p0 = (krel + 0 <= qrel) ? __builtin_amdgcn_exp2f(s[0]) : 0.f;
                    p1 = (krel + 1 <= qrel) ? __builtin_amdgcn_exp2f(s[1]) : 0.f;
                    p2 = (krel + 2 <= qrel) ? __builtin_amdgcn_exp2f(s[2]) : 0.f;
                    p3 = (krel + 3 <= qrel) ? __builtin_amdgcn_exp2f(s[3]) : 0.f;
                } else {
                    p0 = __builtin_amdgcn_exp2f(s[0]);
                    p1 = __builtin_amdgcn_exp2f(s[1]);
                    p2 = __builtin_amdgcn_exp2f(s[2]);
                    p3 = __builtin_amdgcn_exp2f(s[3]);
                }
                ls[qq] += (p0 + p1) + (p2 + p3);
                uint2 pw;
                pw.x = pkbf(p1, p0);
                pw.y = pkbf(p3, p2);
                pa[qq] = __builtin_bit_cast(bf16x4, pw);
            }
            // O += P V (P in registers, A-layout of 16x16x16)
#pragma unroll
            for (int dd = 0; dd < 4; ++dd) {
                const bf16x4 vbf = __builtin_bit_cast(bf16x4, vbr[dd]);
                o[0][dd] = mfma16(pa[0], vbf, o[0][dd]);
                o[1][dd] = mfma16(pa[1], vbf, o[1][dd]);
            }
        }
    }

    // reduce row-sums across quads (lanes sharing cl)
#pragma unroll
    for (int qq = 0; qq < 2; ++qq) {
        float v = ls[qq];
        v += __shfl_xor(v, 16);
        v += __shfl_xor(v, 32);
        ls[qq] = v;
    }
    // normalize + store: row = qw + m*16 + quad*4 + r, col = dd*16 + cl
#pragma unroll
    for (int m = 0; m < 2; ++m)
#pragma unroll
        for (int r = 0; r < 4; ++r) {
            const float inv = 1.0f / __shfl(ls[m], quad * 4 + r);
#pragma unroll
            for (int dd = 0; dd < 4; ++dd)
                Oh[(size_t)(qw + m * 16 + quad * 4 + r) * DHEAD + dd * 16 + cl] = o[m][dd][r] * inv;
        }
}

extern "C" void kernel_launch(void* const* d_in, const int* in_sizes, int n_in,
                              void* d_out, int out_size, void* d_ws, size_t ws_size,
                              hipStream_t stream) {
    const float* Q = (const float*)d_in[0];
    const float* K = (const float*)d_in[1];
    const float* V = (const float*)d_in[2];
    float*       O = (float*)d_out;

    unsigned short* Kbf  = (unsigned short*)d_ws;
    unsigned short* Vtbf = Kbf + NELEM;

    convert_prep<<<dim3(4096 + 512), dim3(256), 0, stream>>>(K, V, Kbf, Vtbf);
    sdpa_mfma<<<dim3(1024), dim3(256), 0, stream>>>(Q, Kbf, Vtbf, O);
}